// Round 2
// baseline (841.604 us; speedup 1.0000x reference)
//
#include <hip/hip_runtime.h>
#include <hip/hip_bf16.h>
#include <math.h>

typedef __attribute__((ext_vector_type(8))) __bf16 bf16x8;
typedef __attribute__((ext_vector_type(4))) float f32x4;

#define MFMA16(a, b, c) __builtin_amdgcn_mfma_f32_16x16x32_bf16((a), (b), (c), 0, 0, 0)

__device__ inline void gld_lds16(const __hip_bfloat16* g, __hip_bfloat16* l) {
    __builtin_amdgcn_global_load_lds(
        (const __attribute__((address_space(1))) void*)g,
        (__attribute__((address_space(3))) void*)l, 16, 0, 0);
}

#define RAW_BARRIER() __builtin_amdgcn_s_barrier()
// rule #18: sched_barrier(0) immediately after an inline-asm lgkmcnt wait
#define WAIT_LGKM0()                                          \
    do {                                                      \
        asm volatile("s_waitcnt lgkmcnt(0)" ::: "memory");    \
        __builtin_amdgcn_sched_barrier(0);                    \
    } while (0)
#define WAIT_VM(N) asm volatile("s_waitcnt vmcnt(" #N ")" ::: "memory")

// ---------------------------------------------------------------------------
// fp32 -> bf16 cast (4 elems/thread)
// ---------------------------------------------------------------------------
__global__ void cast_bf16_kernel(const float* __restrict__ in, __hip_bfloat16* __restrict__ out) {
    int i = (blockIdx.x * blockDim.x + threadIdx.x) * 4;
    float4 v = *(const float4*)(in + i);
    out[i + 0] = __float2bfloat16(v.x);
    out[i + 1] = __float2bfloat16(v.y);
    out[i + 2] = __float2bfloat16(v.z);
    out[i + 3] = __float2bfloat16(v.w);
}

// ---------------------------------------------------------------------------
// W[K][N] fp32 -> Wt[N][K] bf16 (32x32 LDS tile transpose)
// ---------------------------------------------------------------------------
__global__ void transpose_cast_kernel(const float* __restrict__ w, __hip_bfloat16* __restrict__ wt,
                                      int K, int N) {
    __shared__ float tile[32][33];
    int n0 = blockIdx.x * 32, k0 = blockIdx.y * 32;
    int tx = threadIdx.x;  // 0..31
    int ty = threadIdx.y;  // 0..7
#pragma unroll
    for (int r = 0; r < 4; r++) {
        int k = k0 + ty + r * 8;
        tile[ty + r * 8][tx] = w[(size_t)k * N + n0 + tx];
    }
    __syncthreads();
#pragma unroll
    for (int r = 0; r < 4; r++) {
        int n = n0 + ty + r * 8;
        wt[(size_t)n * K + k0 + tx] = __float2bfloat16(tile[tx][ty + r * 8]);
    }
}

// ===========================================================================
// 256x256 8-phase GEMM core (T2+T3+T4+T5 per the m201 template).
// BM=BN=256, BK=64, 8 waves (2M x 4N), per-wave C = 128x64 (acc[8][4]).
// LDS: 2 buffers x (A 256x64 + B 256x64) bf16 = 128 KiB, XOR-swizzled
// 16B chunks (chunk c of row r stored at c^(r&7); swizzle applied via
// per-lane global source address, linear LDS dest — both-sides rule #21).
//
// Per K-tile t, 4 phases:
//  P1: ds_read A m0-3 + B n0-1 | stage B-lo(t+1)->buf^1 | MFMA Q(0,0)
//  P2: ds_read A m4-7          | stage B-hi(t+1)->buf^1 | MFMA Q(1,0)
//  P3: ds_read B n2-3          | stage A-lo(t+2)->buf   | MFMA Q(0,1)
//  P4: (no reads)              | stage A-hi(t+2)->buf   | MFMA Q(1,1) | vmcnt(4)
// Staging A(t+2) into the CURRENT buffer is safe: all A ds_reads of the
// tile complete before P2's second barrier (lgkmcnt(0) precedes it).
// At each boundary 12 loads are outstanding; vmcnt(4) retires exactly the
// 8 the next tile needs (in-order retirement, m135), keeping 2 half-tiles
// in flight across the barrier (T4: never vmcnt(0) in the main loop).
// ===========================================================================
constexpr int TILE = 256 * 64;  // elems per operand per buffer

template <typename EPILOGUE>
__device__ __forceinline__ void gemm256_8phase(
    const __hip_bfloat16* __restrict__ A, const __hip_bfloat16* __restrict__ Bt,
    int m0, int n0, int K, __hip_bfloat16* As, __hip_bfloat16* Bs, EPILOGUE epi) {
    int tid = threadIdx.x;
    int wave = tid >> 6, lane = tid & 63;
    int l15 = lane & 15, quad = lane >> 4;
    int wr = wave >> 2, wc = wave & 3;

    // staging: each instruction covers 8 rows x 8 chunks (64 lanes x 16B)
    int lr = lane >> 3;            // row within 8-row group
    int c8 = (lane & 7) ^ lr;      // pre-swizzled global chunk for this lane
    const __hip_bfloat16* aG = A + (size_t)(m0 + wave * 8 + lr) * K + c8 * 8;
    const __hip_bfloat16* bG = Bt + (size_t)(n0 + wave * 8 + lr) * K + c8 * 8;
    int stRow = wave * 8;

    int e3 = l15 & 7;
    int s0 = (quad ^ e3) * 8;        // kh=0 swizzled slot (elems)
    int s1 = ((4 + quad) ^ e3) * 8;  // kh=1

    f32x4 acc[8][4];
#pragma unroll
    for (int mi = 0; mi < 8; mi++)
#pragma unroll
        for (int ni = 0; ni < 4; ni++) acc[mi][ni] = (f32x4){0.f, 0.f, 0.f, 0.f};

    const int NT = K >> 6;

    auto stA = [&](int buf, int kt, int i) {
        gld_lds16(aG + (size_t)kt * 64 + (size_t)(i * 64) * K,
                  As + buf * TILE + (stRow + i * 64) * 64);
    };
    auto stB = [&](int buf, int kt, int i) {
        gld_lds16(bG + (size_t)kt * 64 + (size_t)(i * 64) * K,
                  Bs + buf * TILE + (stRow + i * 64) * 64);
    };

    // prologue: A(0),B(0)->buf0, A(1)->buf1; wait for tile 0 (oldest 8 of 12)
#pragma unroll
    for (int i = 0; i < 4; i++) stA(0, 0, i);
#pragma unroll
    for (int i = 0; i < 4; i++) stB(0, 0, i);
    {
        int k1 = (1 < NT) ? 1 : 0;
#pragma unroll
        for (int i = 0; i < 4; i++) stA(1, k1, i);
    }
    WAIT_VM(4);
    RAW_BARRIER();

    int cur = 0;
    for (int t = 0; t < NT; ++t) {
        int ktB = (t + 1 < NT) ? t + 1 : NT - 1;  // clamped: data unused past end
        int ktA = (t + 2 < NT) ? t + 2 : NT - 1;
        const __hip_bfloat16* af = As + cur * TILE + (wr * 128 + l15) * 64;
        const __hip_bfloat16* bf = Bs + cur * TILE + (wc * 64 + l15) * 64;
        bf16x8 a0[4][2], a1[4][2], b0[2][2], b1[2][2];

        // ---- phase 1: Q(0,0)
#pragma unroll
        for (int mi = 0; mi < 4; mi++) {
            a0[mi][0] = *(const bf16x8*)(af + mi * 1024 + s0);
            a0[mi][1] = *(const bf16x8*)(af + mi * 1024 + s1);
        }
#pragma unroll
        for (int ni = 0; ni < 2; ni++) {
            b0[ni][0] = *(const bf16x8*)(bf + ni * 1024 + s0);
            b0[ni][1] = *(const bf16x8*)(bf + ni * 1024 + s1);
        }
        stB(cur ^ 1, ktB, 0);
        stB(cur ^ 1, ktB, 1);
        RAW_BARRIER();
        WAIT_LGKM0();
        __builtin_amdgcn_s_setprio(1);
#pragma unroll
        for (int mi = 0; mi < 4; mi++)
#pragma unroll
            for (int ni = 0; ni < 2; ni++) {
                acc[mi][ni] = MFMA16(a0[mi][0], b0[ni][0], acc[mi][ni]);
                acc[mi][ni] = MFMA16(a0[mi][1], b0[ni][1], acc[mi][ni]);
            }
        __builtin_amdgcn_s_setprio(0);
        RAW_BARRIER();

        // ---- phase 2: Q(1,0)
#pragma unroll
        for (int mi = 0; mi < 4; mi++) {
            a1[mi][0] = *(const bf16x8*)(af + (mi + 4) * 1024 + s0);
            a1[mi][1] = *(const bf16x8*)(af + (mi + 4) * 1024 + s1);
        }
        stB(cur ^ 1, ktB, 2);
        stB(cur ^ 1, ktB, 3);
        RAW_BARRIER();
        WAIT_LGKM0();
        __builtin_amdgcn_s_setprio(1);
#pragma unroll
        for (int mi = 0; mi < 4; mi++)
#pragma unroll
            for (int ni = 0; ni < 2; ni++) {
                acc[mi + 4][ni] = MFMA16(a1[mi][0], b0[ni][0], acc[mi + 4][ni]);
                acc[mi + 4][ni] = MFMA16(a1[mi][1], b0[ni][1], acc[mi + 4][ni]);
            }
        __builtin_amdgcn_s_setprio(0);
        RAW_BARRIER();

        // ---- phase 3: Q(0,1)  (A-region of cur fully consumed -> restage)
#pragma unroll
        for (int ni = 0; ni < 2; ni++) {
            b1[ni][0] = *(const bf16x8*)(bf + (ni + 2) * 1024 + s0);
            b1[ni][1] = *(const bf16x8*)(bf + (ni + 2) * 1024 + s1);
        }
        stA(cur, ktA, 0);
        stA(cur, ktA, 1);
        RAW_BARRIER();
        WAIT_LGKM0();
        __builtin_amdgcn_s_setprio(1);
#pragma unroll
        for (int mi = 0; mi < 4; mi++)
#pragma unroll
            for (int ni = 0; ni < 2; ni++) {
                acc[mi][ni + 2] = MFMA16(a0[mi][0], b1[ni][0], acc[mi][ni + 2]);
                acc[mi][ni + 2] = MFMA16(a0[mi][1], b1[ni][1], acc[mi][ni + 2]);
            }
        __builtin_amdgcn_s_setprio(0);
        RAW_BARRIER();

        // ---- phase 4: Q(1,1) + counted vmcnt (never 0 in main loop)
        stA(cur, ktA, 2);
        stA(cur, ktA, 3);
        RAW_BARRIER();
        __builtin_amdgcn_s_setprio(1);
#pragma unroll
        for (int mi = 0; mi < 4; mi++)
#pragma unroll
            for (int ni = 0; ni < 2; ni++) {
                acc[mi + 4][ni + 2] = MFMA16(a1[mi][0], b1[ni][0], acc[mi + 4][ni + 2]);
                acc[mi + 4][ni + 2] = MFMA16(a1[mi][1], b1[ni][1], acc[mi + 4][ni + 2]);
            }
        __builtin_amdgcn_s_setprio(0);
        WAIT_VM(4);
        RAW_BARRIER();
        cur ^= 1;
    }
    WAIT_VM(0);  // drain in-flight LDS-DMA before epilogue / endpgm
    epi(acc, wr, wc, l15, quad);
}

// ---------------------------------------------------------------------------
// Tiled QKV GEMM: M=4096 (b*2048+s), N=6144 (Q|K|V), K=4096.
// V written tile-transposed: Vtt[b][kh][s>>6][d][s&63].
// ---------------------------------------------------------------------------
__global__ __launch_bounds__(512, 2) void gemm_qkv_kernel(
    const __hip_bfloat16* __restrict__ Xb,
    const __hip_bfloat16* __restrict__ Wt,   // [6144][4096]
    __hip_bfloat16* __restrict__ Qraw,
    __hip_bfloat16* __restrict__ Kraw,
    __hip_bfloat16* __restrict__ Vtt) {
    __shared__ __hip_bfloat16 As[2 * TILE];
    __shared__ __hip_bfloat16 Bs[2 * TILE];
    int m0 = blockIdx.y * 256, n0 = blockIdx.x * 256;
    gemm256_8phase(Xb, Wt, m0, n0, 4096, As, Bs,
        [&](f32x4 (&acc)[8][4], int wr, int wc, int l15, int quad) {
#pragma unroll
            for (int mi = 0; mi < 8; mi++) {
#pragma unroll
                for (int ni = 0; ni < 4; ni++) {
                    int n = n0 + wc * 64 + ni * 16 + l15;
#pragma unroll
                    for (int r = 0; r < 4; r++) {
                        int m = m0 + wr * 128 + mi * 16 + quad * 4 + r;
                        int bb = m >> 11, s = m & 2047;
                        __hip_bfloat16 hv = __float2bfloat16(acc[mi][ni][r]);
                        if (n < 4096) {
                            int hh = n >> 7, d = n & 127;
                            Qraw[(((size_t)(bb * 32 + hh)) * 2048 + s) * 128 + d] = hv;
                        } else if (n < 5120) {
                            int n2 = n - 4096, hh = n2 >> 7, d = n2 & 127;
                            Kraw[(((size_t)(bb * 8 + hh)) * 2048 + s) * 128 + d] = hv;
                        } else {
                            int n2 = n - 5120, hh = n2 >> 7, d = n2 & 127;
                            Vtt[((((size_t)(bb * 8 + hh)) * 32 + (s >> 6)) * 128 + d) * 64 + (s & 63)] = hv;
                        }
                    }
                }
            }
        });
}

// ---------------------------------------------------------------------------
// Tiled output GEMM: out[m][n] = AO[m][:] . Wot[n][:], fp32 out. M=N=K=4096.
// ---------------------------------------------------------------------------
__global__ __launch_bounds__(512, 2) void gemm_out_kernel(
    const __hip_bfloat16* __restrict__ A, const __hip_bfloat16* __restrict__ Bt,
    float* __restrict__ C) {
    __shared__ __hip_bfloat16 As[2 * TILE];
    __shared__ __hip_bfloat16 Bs[2 * TILE];
    int m0 = blockIdx.y * 256, n0 = blockIdx.x * 256;
    gemm256_8phase(A, Bt, m0, n0, 4096, As, Bs,
        [&](f32x4 (&acc)[8][4], int wr, int wc, int l15, int quad) {
            const int N = 4096;
#pragma unroll
            for (int mi = 0; mi < 8; mi++) {
#pragma unroll
                for (int ni = 0; ni < 4; ni++) {
                    int n = n0 + wc * 64 + ni * 16 + l15;
#pragma unroll
                    for (int r = 0; r < 4; r++) {
                        int m = m0 + wr * 128 + mi * 16 + quad * 4 + r;
                        C[(size_t)m * N + n] = acc[mi][ni][r];
                    }
                }
            }
        });
}

// ---------------------------------------------------------------------------
// In-place RoPE on x[b][h][s][128] bf16. One thread per (b,h,s,d<64) pair.
// ---------------------------------------------------------------------------
__global__ void rope_kernel(__hip_bfloat16* __restrict__ x, const int* __restrict__ pos_ids,
                            int nheads) {
    int idx = blockIdx.x * blockDim.x + threadIdx.x;
    int d = idx & 63;
    int s = (idx >> 6) & 2047;
    int bh = idx >> 17;
    int b = bh / nheads;
    float p = (float)pos_ids[b * 2048 + s];
    float inv = exp2f(-(float)d * 0.31143075889f);  // THETA^(-d/64), log2(1e6)/64
    float ang = p * inv;
    float sn, cs;
    __sincosf(ang, &sn, &cs);
    size_t base = ((size_t)bh * 2048 + s) * 128;
    float x1 = __bfloat162float(x[base + d]);
    float x2 = __bfloat162float(x[base + d + 64]);
    x[base + d]      = __float2bfloat16(x1 * cs - x2 * sn);
    x[base + d + 64] = __float2bfloat16(x2 * cs + x1 * sn);
}

// ---------------------------------------------------------------------------
// Flash attention v4 (unchanged): block-cooperative LDS staging,
// 64-key tiles, XOR-swizzled K/V, fixed-shift softmax, wave-private P.
// ---------------------------------------------------------------------------
__global__ __launch_bounds__(256) void attn_kernel(
    const __hip_bfloat16* __restrict__ Qb, const __hip_bfloat16* __restrict__ Kb,
    const __hip_bfloat16* __restrict__ Vtt, __hip_bfloat16* __restrict__ AO) {
    const int S = 2048, D = 128;
    __shared__ __hip_bfloat16 Ks[64 * 128];
    __shared__ __hip_bfloat16 Vs[128 * 64];
    __shared__ __hip_bfloat16 Pl[4][16][72];

    int tid = threadIdx.x;
    int wave = tid >> 6, lane = tid & 63;
    int l15 = lane & 15, quad = lane >> 4;
    int base = blockIdx.x * 64;
    int i0 = base + wave * 16;
    int h = blockIdx.y, b = blockIdx.z;
    int kh = h >> 2;
    const __hip_bfloat16* Qh = Qb + (size_t)(b * 32 + h) * S * D;
    const __hip_bfloat16* Kh = Kb + (size_t)(b * 8 + kh) * S * D;
    const __hip_bfloat16* Vh = Vtt + (size_t)(b * 8 + kh) * S * D;

    bf16x8 qf[4];
    {
        const __hip_bfloat16* qrow = Qh + (size_t)(i0 + l15) * D + quad * 8;
#pragma unroll
        for (int kk = 0; kk < 4; kk++) qf[kk] = *(const bf16x8*)(qrow + kk * 32);
    }
    f32x4 o[8];
#pragma unroll
    for (int f = 0; f < 8; f++) o[f] = (f32x4){0.f, 0.f, 0.f, 0.f};
    float lrow[4] = {0.f, 0.f, 0.f, 0.f};

    int kst = (base > 1023) ? ((base - 1023) & ~63) : 0;
    const float c2 = 0.12751878882f;  // (1/sqrt(128)) * log2(e)
    int e3 = l15 & 7;

    for (int key0 = kst; key0 <= base; key0 += 64) {
#pragma unroll
        for (int i = 0; i < 4; i++) {
            int rb = wave * 16 + i * 4;
            int row = rb + (lane >> 4);
            int c = (lane & 15) ^ (row & 7);
            gld_lds16(Kh + (size_t)(key0 + row) * 128 + c * 8, Ks + rb * 128);
        }
        const __hip_bfloat16* Vtile = Vh + (size_t)(key0 >> 6) * (128 * 64);
#pragma unroll
        for (int i = 0; i < 4; i++) {
            int db = wave * 32 + i * 8;
            int row = db + (lane >> 3);
            int c = (lane & 7) ^ (row & 7);
            gld_lds16(Vtile + (size_t)row * 64 + c * 8, Vs + db * 64);
        }
        __syncthreads();

        bool alive = (key0 <= i0 + 15) && (key0 + 63 >= i0 - 1023);
        if (alive) {
            f32x4 sc[4];
#pragma unroll
            for (int kb = 0; kb < 4; kb++) {
                sc[kb] = (f32x4){0.f, 0.f, 0.f, 0.f};
                const __hip_bfloat16* krow = Ks + (kb * 16 + l15) * 128;
#pragma unroll
                for (int kk = 0; kk < 4; kk++) {
                    int slot = ((kk << 2) | quad) ^ e3;
                    bf16x8 kf = *(const bf16x8*)(krow + slot * 8);
                    sc[kb] = MFMA16(qf[kk], kf, sc[kb]);
                }
            }
            bool interior = (key0 + 63 <= i0) && (key0 >= i0 - 1008);
            if (interior) {
#pragma unroll
                for (int kb = 0; kb < 4; kb++)
#pragma unroll
                    for (int r = 0; r < 4; r++) {
                        float p = __builtin_amdgcn_exp2f(sc[kb][r] * c2);
                        lrow[r] += p;
                        Pl[wave][quad * 4 + r][kb * 16 + l15] = __float2bfloat16(p);
                    }
            } else {
#pragma unroll
                for (int kb = 0; kb < 4; kb++)
#pragma unroll
                    for (int r = 0; r < 4; r++) {
                        int i = i0 + quad * 4 + r;
                        int j = key0 + kb * 16 + l15;
                        float v = (j <= i && i - j < 1024) ? sc[kb][r] * c2 : -1e30f;
                        float p = __builtin_amdgcn_exp2f(v);
                        lrow[r] += p;
                        Pl[wave][quad * 4 + r][kb * 16 + l15] = __float2bfloat16(p);
                    }
            }
            bf16x8 pf0 = *(const bf16x8*)(&Pl[wave][l15][quad * 8]);
            bf16x8 pf1 = *(const bf16x8*)(&Pl[wave][l15][32 + quad * 8]);
            int s0 = quad ^ e3, s1 = (4 + quad) ^ e3;
#pragma unroll
            for (int f = 0; f < 8; f++) {
                const __hip_bfloat16* vrow = Vs + (f * 16 + l15) * 64;
                bf16x8 v0 = *(const bf16x8*)(vrow + s0 * 8);
                bf16x8 v1 = *(const bf16x8*)(vrow + s1 * 8);
                o[f] = MFMA16(pf0, v0, o[f]);
                o[f] = MFMA16(pf1, v1, o[f]);
            }
        }
        __syncthreads();
    }

#pragma unroll
    for (int r = 0; r < 4; r++) {
#pragma unroll
        for (int msk = 1; msk < 16; msk <<= 1) lrow[r] += __shfl_xor(lrow[r], msk, 64);
    }
#pragma unroll
    for (int r = 0; r < 4; r++) {
        int srow = i0 + quad * 4 + r;
        float invl = 1.f / lrow[r];
        __hip_bfloat16* orow = AO + ((size_t)(b * 2048 + srow) * 4096) + h * 128;
#pragma unroll
        for (int f = 0; f < 8; f++) orow[f * 16 + l15] = __float2bfloat16(o[f][r] * invl);
    }
}

// ---------------------------------------------------------------------------
extern "C" void kernel_launch(void* const* d_in, const int* in_sizes, int n_in,
                              void* d_out, int out_size, void* d_ws, size_t ws_size,
                              hipStream_t stream) {
    (void)in_sizes; (void)n_in; (void)out_size;
    const float* hidden = (const float*)d_in[0];
    const int* pos = (const int*)d_in[1];
    const float* wq = (const float*)d_in[2];
    const float* wk = (const float*)d_in[3];
    const float* wv = (const float*)d_in[4];
    const float* wo = (const float*)d_in[5];
    float* out = (float*)d_out;

    const int M = 4096;  // B*S
    char* ws = (char*)d_ws;
    size_t off = 0;
    auto alloc = [&](size_t bytes) { char* p = ws + off; off += bytes; return p; };
    __hip_bfloat16* Xb    = (__hip_bfloat16*)alloc((size_t)M * 4096 * 2);
    __hip_bfloat16* Wqkvt = (__hip_bfloat16*)alloc((size_t)6144 * 4096 * 2);
    __hip_bfloat16* Wot   = (__hip_bfloat16*)alloc((size_t)4096 * 4096 * 2);
    __hip_bfloat16* Qb    = (__hip_bfloat16*)alloc((size_t)M * 4096 * 2);
    __hip_bfloat16* Kb    = (__hip_bfloat16*)alloc((size_t)M * 1024 * 2);
    __hip_bfloat16* Vtt   = (__hip_bfloat16*)alloc((size_t)M * 1024 * 2);
    __hip_bfloat16* AO    = (__hip_bfloat16*)alloc((size_t)M * 4096 * 2);
    if (off > ws_size) return;

    cast_bf16_kernel<<<(M * 4096) / 1024, 256, 0, stream>>>(hidden, Xb);
    dim3 tb(32, 8);
    transpose_cast_kernel<<<dim3(128, 128), tb, 0, stream>>>(wq, Wqkvt, 4096, 4096);
    transpose_cast_kernel<<<dim3(32, 128),  tb, 0, stream>>>(wk, Wqkvt + (size_t)4096 * 4096, 4096, 1024);
    transpose_cast_kernel<<<dim3(32, 128),  tb, 0, stream>>>(wv, Wqkvt + (size_t)5120 * 4096, 4096, 1024);
    transpose_cast_kernel<<<dim3(128, 128), tb, 0, stream>>>(wo, Wot, 4096, 4096);

    gemm_qkv_kernel<<<dim3(24, 16), 512, 0, stream>>>(Xb, Wqkvt, Qb, Kb, Vtt);

    rope_kernel<<<(2 * 32 * 2048 * 64) / 256, 256, 0, stream>>>(Qb, pos, 32);
    rope_kernel<<<(2 * 8 * 2048 * 64) / 256, 256, 0, stream>>>(Kb, pos, 8);

    attn_kernel<<<dim3(32, 32, 2), 256, 0, stream>>>(Qb, Kb, Vtt, AO);

    gemm_out_kernel<<<dim3(16, 16), 512, 0, stream>>>(AO, Wot, out);
}

// Round 3
// 809.598 us; speedup vs baseline: 1.0395x; 1.0395x over previous
//
#include <hip/hip_runtime.h>
#include <hip/hip_bf16.h>
#include <math.h>

typedef __attribute__((ext_vector_type(8))) __bf16 bf16x8;
typedef __attribute__((ext_vector_type(4))) float f32x4;

#define MFMA16(a, b, c) __builtin_amdgcn_mfma_f32_16x16x32_bf16((a), (b), (c), 0, 0, 0)

__device__ inline void gld_lds16(const __hip_bfloat16* g, __hip_bfloat16* l) {
    __builtin_amdgcn_global_load_lds(
        (const __attribute__((address_space(1))) void*)g,
        (__attribute__((address_space(3))) void*)l, 16, 0, 0);
}

#define RAW_BARRIER() __builtin_amdgcn_s_barrier()
// rule #18: sched_barrier(0) immediately after an inline-asm lgkmcnt wait
#define WAIT_LGKM0()                                          \
    do {                                                      \
        asm volatile("s_waitcnt lgkmcnt(0)" ::: "memory");    \
        __builtin_amdgcn_sched_barrier(0);                    \
    } while (0)
#define WAIT_VM(N) asm volatile("s_waitcnt vmcnt(" #N ")" ::: "memory")

// ---------------------------------------------------------------------------
// fp32 -> bf16 cast (4 elems/thread)
// ---------------------------------------------------------------------------
__global__ void cast_bf16_kernel(const float* __restrict__ in, __hip_bfloat16* __restrict__ out) {
    int i = (blockIdx.x * blockDim.x + threadIdx.x) * 4;
    float4 v = *(const float4*)(in + i);
    out[i + 0] = __float2bfloat16(v.x);
    out[i + 1] = __float2bfloat16(v.y);
    out[i + 2] = __float2bfloat16(v.z);
    out[i + 3] = __float2bfloat16(v.w);
}

// ---------------------------------------------------------------------------
// W[K][N] fp32 -> Wt[N][K] bf16 (32x32 LDS tile transpose)
// ---------------------------------------------------------------------------
__global__ void transpose_cast_kernel(const float* __restrict__ w, __hip_bfloat16* __restrict__ wt,
                                      int K, int N) {
    __shared__ float tile[32][33];
    int n0 = blockIdx.x * 32, k0 = blockIdx.y * 32;
    int tx = threadIdx.x;  // 0..31
    int ty = threadIdx.y;  // 0..7
#pragma unroll
    for (int r = 0; r < 4; r++) {
        int k = k0 + ty + r * 8;
        tile[ty + r * 8][tx] = w[(size_t)k * N + n0 + tx];
    }
    __syncthreads();
#pragma unroll
    for (int r = 0; r < 4; r++) {
        int n = n0 + ty + r * 8;
        wt[(size_t)n * K + k0 + tx] = __float2bfloat16(tile[tx][ty + r * 8]);
    }
}

// ===========================================================================
// BK=64 XOR-swizzled GEMM core, 128x128 tile (R0 known-good: ~687 TF, smooth
// 1536-block grid for QKV). 2 barriers per K-tile, __syncthreads drain.
// ===========================================================================
template <typename EPILOGUE>
__device__ __forceinline__ void gemm128_bk64(
    const __hip_bfloat16* __restrict__ A, const __hip_bfloat16* __restrict__ Bt,
    int m0, int n0, int K, __hip_bfloat16* As, __hip_bfloat16* Bs, EPILOGUE epi) {
    int tid = threadIdx.x;
    int wave = tid >> 6, lane = tid & 63;
    int l15 = lane & 15, quad = lane >> 4;

    // staging: lane -> (row-in-8, stored-chunk); global chunk = stored ^ (row&7)
    int lr = lane >> 3;                    // 0..7 row within 8-row group
    int c8 = (lane & 7) ^ lr;              // global chunk index for this lane
    const __hip_bfloat16* aG = A + (size_t)(m0 + wave * 8 + lr) * K + c8 * 8;
    const __hip_bfloat16* bG = Bt + (size_t)(n0 + wave * 8 + lr) * K + c8 * 8;
    __hip_bfloat16* aL = As + wave * 512;  // (wave*8 rows)*64
    __hip_bfloat16* bL = Bs + wave * 512;

    int wm = wave & 1, wn = wave >> 1;
    int e3 = l15 & 7;
    int s0 = (quad ^ e3) * 8;              // kh=0 slot offset (elements)
    int s1 = ((4 + quad) ^ e3) * 8;        // kh=1
    const __hip_bfloat16* afr = As + (wm * 64 + l15) * 64;
    const __hip_bfloat16* bfr = Bs + (wn * 64 + l15) * 64;

    f32x4 acc[4][4];
#pragma unroll
    for (int mi = 0; mi < 4; mi++)
#pragma unroll
        for (int ni = 0; ni < 4; ni++) acc[mi][ni] = (f32x4){0.f, 0.f, 0.f, 0.f};

    for (int k0 = 0; k0 < K; k0 += 64) {
#pragma unroll
        for (int i = 0; i < 4; i++) {
            gld_lds16(aG + k0 + (size_t)(i * 32) * K, aL + i * 2048);
            gld_lds16(bG + k0 + (size_t)(i * 32) * K, bL + i * 2048);
        }
        __syncthreads();
        bf16x8 a0[4], b0[4], a1[4], b1[4];
#pragma unroll
        for (int mi = 0; mi < 4; mi++) {
            a0[mi] = *(const bf16x8*)(afr + mi * 1024 + s0);
            a1[mi] = *(const bf16x8*)(afr + mi * 1024 + s1);
        }
#pragma unroll
        for (int ni = 0; ni < 4; ni++) {
            b0[ni] = *(const bf16x8*)(bfr + ni * 1024 + s0);
            b1[ni] = *(const bf16x8*)(bfr + ni * 1024 + s1);
        }
#pragma unroll
        for (int mi = 0; mi < 4; mi++)
#pragma unroll
            for (int ni = 0; ni < 4; ni++) {
                acc[mi][ni] = MFMA16(a0[mi], b0[ni], acc[mi][ni]);
                acc[mi][ni] = MFMA16(a1[mi], b1[ni], acc[mi][ni]);
            }
        __syncthreads();
    }
    epi(acc, wm, wn, l15, quad);
}

// ---------------------------------------------------------------------------
// Tiled QKV GEMM (128x128 core): M=4096, N=6144 (Q|K|V), K=4096.
// V written tile-transposed: Vtt[b][kh][s>>6][d][s&63].
// ---------------------------------------------------------------------------
__global__ __launch_bounds__(256) void gemm_qkv_kernel(
    const __hip_bfloat16* __restrict__ Xb,
    const __hip_bfloat16* __restrict__ Wt,   // [6144][4096]
    __hip_bfloat16* __restrict__ Qraw,
    __hip_bfloat16* __restrict__ Kraw,
    __hip_bfloat16* __restrict__ Vtt) {
    __shared__ __hip_bfloat16 As[128 * 64];
    __shared__ __hip_bfloat16 Bs[128 * 64];
    int m0 = blockIdx.y * 128, n0 = blockIdx.x * 128;
    gemm128_bk64(Xb, Wt, m0, n0, 4096, As, Bs,
        [&](f32x4 (&acc)[4][4], int wm, int wn, int l15, int quad) {
#pragma unroll
            for (int mi = 0; mi < 4; mi++) {
#pragma unroll
                for (int ni = 0; ni < 4; ni++) {
                    int n = n0 + wn * 64 + ni * 16 + l15;
#pragma unroll
                    for (int r = 0; r < 4; r++) {
                        int m = m0 + wm * 64 + mi * 16 + quad * 4 + r;
                        int bb = m >> 11, s = m & 2047;
                        __hip_bfloat16 hv = __float2bfloat16(acc[mi][ni][r]);
                        if (n < 4096) {
                            int hh = n >> 7, d = n & 127;
                            Qraw[(((size_t)(bb * 32 + hh)) * 2048 + s) * 128 + d] = hv;
                        } else if (n < 5120) {
                            int n2 = n - 4096, hh = n2 >> 7, d = n2 & 127;
                            Kraw[(((size_t)(bb * 8 + hh)) * 2048 + s) * 128 + d] = hv;
                        } else {
                            int n2 = n - 5120, hh = n2 >> 7, d = n2 & 127;
                            Vtt[((((size_t)(bb * 8 + hh)) * 32 + (s >> 6)) * 128 + d) * 64 + (s & 63)] = hv;
                        }
                    }
                }
            }
        });
}

// ===========================================================================
// 256x256 8-phase core (verified R1) — used ONLY for gemm_out, whose
// 16x16 = 256-block grid is perfectly quantized at 1 block/CU (no tail).
// ===========================================================================
constexpr int TILE = 256 * 64;  // elems per operand per buffer

template <typename EPILOGUE>
__device__ __forceinline__ void gemm256_8phase(
    const __hip_bfloat16* __restrict__ A, const __hip_bfloat16* __restrict__ Bt,
    int m0, int n0, int K, __hip_bfloat16* As, __hip_bfloat16* Bs, EPILOGUE epi) {
    int tid = threadIdx.x;
    int wave = tid >> 6, lane = tid & 63;
    int l15 = lane & 15, quad = lane >> 4;
    int wr = wave >> 2, wc = wave & 3;

    int lr = lane >> 3;            // row within 8-row group
    int c8 = (lane & 7) ^ lr;      // pre-swizzled global chunk for this lane
    const __hip_bfloat16* aG = A + (size_t)(m0 + wave * 8 + lr) * K + c8 * 8;
    const __hip_bfloat16* bG = Bt + (size_t)(n0 + wave * 8 + lr) * K + c8 * 8;
    int stRow = wave * 8;

    int e3 = l15 & 7;
    int s0 = (quad ^ e3) * 8;        // kh=0 swizzled slot (elems)
    int s1 = ((4 + quad) ^ e3) * 8;  // kh=1

    f32x4 acc[8][4];
#pragma unroll
    for (int mi = 0; mi < 8; mi++)
#pragma unroll
        for (int ni = 0; ni < 4; ni++) acc[mi][ni] = (f32x4){0.f, 0.f, 0.f, 0.f};

    const int NT = K >> 6;

    auto stA = [&](int buf, int kt, int i) {
        gld_lds16(aG + (size_t)kt * 64 + (size_t)(i * 64) * K,
                  As + buf * TILE + (stRow + i * 64) * 64);
    };
    auto stB = [&](int buf, int kt, int i) {
        gld_lds16(bG + (size_t)kt * 64 + (size_t)(i * 64) * K,
                  Bs + buf * TILE + (stRow + i * 64) * 64);
    };

#pragma unroll
    for (int i = 0; i < 4; i++) stA(0, 0, i);
#pragma unroll
    for (int i = 0; i < 4; i++) stB(0, 0, i);
    {
        int k1 = (1 < NT) ? 1 : 0;
#pragma unroll
        for (int i = 0; i < 4; i++) stA(1, k1, i);
    }
    WAIT_VM(4);
    RAW_BARRIER();

    int cur = 0;
    for (int t = 0; t < NT; ++t) {
        int ktB = (t + 1 < NT) ? t + 1 : NT - 1;
        int ktA = (t + 2 < NT) ? t + 2 : NT - 1;
        const __hip_bfloat16* af = As + cur * TILE + (wr * 128 + l15) * 64;
        const __hip_bfloat16* bf = Bs + cur * TILE + (wc * 64 + l15) * 64;
        bf16x8 a0[4][2], a1[4][2], b0[2][2], b1[2][2];

        // ---- phase 1: Q(0,0)
#pragma unroll
        for (int mi = 0; mi < 4; mi++) {
            a0[mi][0] = *(const bf16x8*)(af + mi * 1024 + s0);
            a0[mi][1] = *(const bf16x8*)(af + mi * 1024 + s1);
        }
#pragma unroll
        for (int ni = 0; ni < 2; ni++) {
            b0[ni][0] = *(const bf16x8*)(bf + ni * 1024 + s0);
            b0[ni][1] = *(const bf16x8*)(bf + ni * 1024 + s1);
        }
        stB(cur ^ 1, ktB, 0);
        stB(cur ^ 1, ktB, 1);
        RAW_BARRIER();
        WAIT_LGKM0();
        __builtin_amdgcn_s_setprio(1);
#pragma unroll
        for (int mi = 0; mi < 4; mi++)
#pragma unroll
            for (int ni = 0; ni < 2; ni++) {
                acc[mi][ni] = MFMA16(a0[mi][0], b0[ni][0], acc[mi][ni]);
                acc[mi][ni] = MFMA16(a0[mi][1], b0[ni][1], acc[mi][ni]);
            }
        __builtin_amdgcn_s_setprio(0);
        RAW_BARRIER();

        // ---- phase 2: Q(1,0)
#pragma unroll
        for (int mi = 0; mi < 4; mi++) {
            a1[mi][0] = *(const bf16x8*)(af + (mi + 4) * 1024 + s0);
            a1[mi][1] = *(const bf16x8*)(af + (mi + 4) * 1024 + s1);
        }
        stB(cur ^ 1, ktB, 2);
        stB(cur ^ 1, ktB, 3);
        RAW_BARRIER();
        WAIT_LGKM0();
        __builtin_amdgcn_s_setprio(1);
#pragma unroll
        for (int mi = 0; mi < 4; mi++)
#pragma unroll
            for (int ni = 0; ni < 2; ni++) {
                acc[mi + 4][ni] = MFMA16(a1[mi][0], b0[ni][0], acc[mi + 4][ni]);
                acc[mi + 4][ni] = MFMA16(a1[mi][1], b0[ni][1], acc[mi + 4][ni]);
            }
        __builtin_amdgcn_s_setprio(0);
        RAW_BARRIER();

        // ---- phase 3: Q(0,1)  (A-region of cur fully consumed -> restage)
#pragma unroll
        for (int ni = 0; ni < 2; ni++) {
            b1[ni][0] = *(const bf16x8*)(bf + (ni + 2) * 1024 + s0);
            b1[ni][1] = *(const bf16x8*)(bf + (ni + 2) * 1024 + s1);
        }
        stA(cur, ktA, 0);
        stA(cur, ktA, 1);
        RAW_BARRIER();
        WAIT_LGKM0();
        __builtin_amdgcn_s_setprio(1);
#pragma unroll
        for (int mi = 0; mi < 4; mi++)
#pragma unroll
            for (int ni = 0; ni < 2; ni++) {
                acc[mi][ni + 2] = MFMA16(a0[mi][0], b1[ni][0], acc[mi][ni + 2]);
                acc[mi][ni + 2] = MFMA16(a0[mi][1], b1[ni][1], acc[mi][ni + 2]);
            }
        __builtin_amdgcn_s_setprio(0);
        RAW_BARRIER();

        // ---- phase 4: Q(1,1) + counted vmcnt (never 0 in main loop)
        stA(cur, ktA, 2);
        stA(cur, ktA, 3);
        RAW_BARRIER();
        __builtin_amdgcn_s_setprio(1);
#pragma unroll
        for (int mi = 0; mi < 4; mi++)
#pragma unroll
            for (int ni = 0; ni < 2; ni++) {
                acc[mi + 4][ni + 2] = MFMA16(a1[mi][0], b1[ni][0], acc[mi + 4][ni + 2]);
                acc[mi + 4][ni + 2] = MFMA16(a1[mi][1], b1[ni][1], acc[mi + 4][ni + 2]);
            }
        __builtin_amdgcn_s_setprio(0);
        WAIT_VM(4);
        RAW_BARRIER();
        cur ^= 1;
    }
    WAIT_VM(0);  // drain in-flight LDS-DMA before epilogue / endpgm
    epi(acc, wr, wc, l15, quad);
}

// ---------------------------------------------------------------------------
// Tiled output GEMM: out[m][n] = AO[m][:] . Wot[n][:], fp32 out. M=N=K=4096.
// ---------------------------------------------------------------------------
__global__ __launch_bounds__(512, 2) void gemm_out_kernel(
    const __hip_bfloat16* __restrict__ A, const __hip_bfloat16* __restrict__ Bt,
    float* __restrict__ C) {
    __shared__ __hip_bfloat16 As[2 * TILE];
    __shared__ __hip_bfloat16 Bs[2 * TILE];
    int m0 = blockIdx.y * 256, n0 = blockIdx.x * 256;
    gemm256_8phase(A, Bt, m0, n0, 4096, As, Bs,
        [&](f32x4 (&acc)[8][4], int wr, int wc, int l15, int quad) {
            const int N = 4096;
#pragma unroll
            for (int mi = 0; mi < 8; mi++) {
#pragma unroll
                for (int ni = 0; ni < 4; ni++) {
                    int n = n0 + wc * 64 + ni * 16 + l15;
#pragma unroll
                    for (int r = 0; r < 4; r++) {
                        int m = m0 + wr * 128 + mi * 16 + quad * 4 + r;
                        C[(size_t)m * N + n] = acc[mi][ni][r];
                    }
                }
            }
        });
}

// ---------------------------------------------------------------------------
// In-place RoPE on x[b][h][s][128] bf16. One thread per (b,h,s,d<64) pair.
// ---------------------------------------------------------------------------
__global__ void rope_kernel(__hip_bfloat16* __restrict__ x, const int* __restrict__ pos_ids,
                            int nheads) {
    int idx = blockIdx.x * blockDim.x + threadIdx.x;
    int d = idx & 63;
    int s = (idx >> 6) & 2047;
    int bh = idx >> 17;
    int b = bh / nheads;
    float p = (float)pos_ids[b * 2048 + s];
    float inv = exp2f(-(float)d * 0.31143075889f);  // THETA^(-d/64), log2(1e6)/64
    float ang = p * inv;
    float sn, cs;
    __sincosf(ang, &sn, &cs);
    size_t base = ((size_t)bh * 2048 + s) * 128;
    float x1 = __bfloat162float(x[base + d]);
    float x2 = __bfloat162float(x[base + d + 64]);
    x[base + d]      = __float2bfloat16(x1 * cs - x2 * sn);
    x[base + d + 64] = __float2bfloat16(x2 * cs + x1 * sn);
}

// ---------------------------------------------------------------------------
// Flash attention v5: double-buffered K/V with counted vmcnt(8) + raw
// barriers (issue tile t+1's DMAs before waiting on tile t's -> HBM/L2
// latency hides under compute), setprio around MFMA clusters.
// Buffer-reuse safety: stage(t+1)->buf[p^1] at iter t overwrites the buffer
// read in iter t-1, which is protected by iter t-1's end-of-iter barrier.
// ---------------------------------------------------------------------------
__global__ __launch_bounds__(256) void attn_kernel(
    const __hip_bfloat16* __restrict__ Qb, const __hip_bfloat16* __restrict__ Kb,
    const __hip_bfloat16* __restrict__ Vtt, __hip_bfloat16* __restrict__ AO) {
    const int S = 2048, D = 128;
    __shared__ __hip_bfloat16 Ks[2][64 * 128];
    __shared__ __hip_bfloat16 Vs[2][128 * 64];
    __shared__ __hip_bfloat16 Pl[4][16][72];

    int tid = threadIdx.x;
    int wave = tid >> 6, lane = tid & 63;
    int l15 = lane & 15, quad = lane >> 4;
    int base = blockIdx.x * 64;
    int i0 = base + wave * 16;
    int h = blockIdx.y, b = blockIdx.z;
    int kh = h >> 2;
    const __hip_bfloat16* Qh = Qb + (size_t)(b * 32 + h) * S * D;
    const __hip_bfloat16* Kh = Kb + (size_t)(b * 8 + kh) * S * D;
    const __hip_bfloat16* Vh = Vtt + (size_t)(b * 8 + kh) * S * D;

    bf16x8 qf[4];
    {
        const __hip_bfloat16* qrow = Qh + (size_t)(i0 + l15) * D + quad * 8;
#pragma unroll
        for (int kk = 0; kk < 4; kk++) qf[kk] = *(const bf16x8*)(qrow + kk * 32);
    }
    f32x4 o[8];
#pragma unroll
    for (int f = 0; f < 8; f++) o[f] = (f32x4){0.f, 0.f, 0.f, 0.f};
    float lrow[4] = {0.f, 0.f, 0.f, 0.f};

    int kst = (base > 1023) ? ((base - 1023) & ~63) : 0;
    const float c2 = 0.12751878882f;  // (1/sqrt(128)) * log2(e)
    int e3 = l15 & 7;

    // stage one 64-key tile (K: 64x128, V: 128x64 transposed) into buf.
    // 8 gld_lds per wave per tile.
    auto stage = [&](int key0, int buf) {
#pragma unroll
        for (int i = 0; i < 4; i++) {
            int rb = wave * 16 + i * 4;
            int row = rb + (lane >> 4);
            int c = (lane & 15) ^ (row & 7);
            gld_lds16(Kh + (size_t)(key0 + row) * 128 + c * 8, &Ks[buf][rb * 128]);
        }
        const __hip_bfloat16* Vtile = Vh + (size_t)(key0 >> 6) * (128 * 64);
#pragma unroll
        for (int i = 0; i < 4; i++) {
            int db = wave * 32 + i * 8;
            int row = db + (lane >> 3);
            int c = (lane & 7) ^ (row & 7);
            gld_lds16(Vtile + (size_t)row * 64 + c * 8, &Vs[buf][db * 64]);
        }
    };

    stage(kst, 0);

    for (int key0 = kst; key0 <= base; key0 += 64) {
        int buf = ((key0 - kst) >> 6) & 1;
        if (key0 + 64 <= base) {
            stage(key0 + 64, buf ^ 1);  // issue next tile's DMAs first
            WAIT_VM(8);                 // then wait only for tile t's 8
        } else {
            WAIT_VM(0);                 // last tile: drain
        }
        RAW_BARRIER();

        bool alive = (key0 <= i0 + 15) && (key0 + 63 >= i0 - 1023);
        if (alive) {
            f32x4 sc[4];
            __builtin_amdgcn_s_setprio(1);
#pragma unroll
            for (int kb = 0; kb < 4; kb++) {
                sc[kb] = (f32x4){0.f, 0.f, 0.f, 0.f};
                const __hip_bfloat16* krow = &Ks[buf][(kb * 16 + l15) * 128];
#pragma unroll
                for (int kk = 0; kk < 4; kk++) {
                    int slot = ((kk << 2) | quad) ^ e3;
                    bf16x8 kf = *(const bf16x8*)(krow + slot * 8);
                    sc[kb] = MFMA16(qf[kk], kf, sc[kb]);
                }
            }
            __builtin_amdgcn_s_setprio(0);
            bool interior = (key0 + 63 <= i0) && (key0 >= i0 - 1008);
            if (interior) {
#pragma unroll
                for (int kb = 0; kb < 4; kb++)
#pragma unroll
                    for (int r = 0; r < 4; r++) {
                        float p = __builtin_amdgcn_exp2f(sc[kb][r] * c2);
                        lrow[r] += p;
                        Pl[wave][quad * 4 + r][kb * 16 + l15] = __float2bfloat16(p);
                    }
            } else {
#pragma unroll
                for (int kb = 0; kb < 4; kb++)
#pragma unroll
                    for (int r = 0; r < 4; r++) {
                        int i = i0 + quad * 4 + r;
                        int j = key0 + kb * 16 + l15;
                        float v = (j <= i && i - j < 1024) ? sc[kb][r] * c2 : -1e30f;
                        float p = __builtin_amdgcn_exp2f(v);
                        lrow[r] += p;
                        Pl[wave][quad * 4 + r][kb * 16 + l15] = __float2bfloat16(p);
                    }
            }
            bf16x8 pf0 = *(const bf16x8*)(&Pl[wave][l15][quad * 8]);
            bf16x8 pf1 = *(const bf16x8*)(&Pl[wave][l15][32 + quad * 8]);
            int s0 = quad ^ e3, s1 = (4 + quad) ^ e3;
            __builtin_amdgcn_s_setprio(1);
#pragma unroll
            for (int f = 0; f < 8; f++) {
                const __hip_bfloat16* vrow = &Vs[buf][(f * 16 + l15) * 64];
                bf16x8 v0 = *(const bf16x8*)(vrow + s0 * 8);
                bf16x8 v1 = *(const bf16x8*)(vrow + s1 * 8);
                o[f] = MFMA16(pf0, v0, o[f]);
                o[f] = MFMA16(pf1, v1, o[f]);
            }
            __builtin_amdgcn_s_setprio(0);
        }
        RAW_BARRIER();  // read-done rendezvous: protects buf^1 overwrite next iter
    }

#pragma unroll
    for (int r = 0; r < 4; r++) {
#pragma unroll
        for (int msk = 1; msk < 16; msk <<= 1) lrow[r] += __shfl_xor(lrow[r], msk, 64);
    }
#pragma unroll
    for (int r = 0; r < 4; r++) {
        int srow = i0 + quad * 4 + r;
        float invl = 1.f / lrow[r];
        __hip_bfloat16* orow = AO + ((size_t)(b * 2048 + srow) * 4096) + h * 128;
#pragma unroll
        for (int f = 0; f < 8; f++) orow[f * 16 + l15] = __float2bfloat16(o[f][r] * invl);
    }
}

// ---------------------------------------------------------------------------
extern "C" void kernel_launch(void* const* d_in, const int* in_sizes, int n_in,
                              void* d_out, int out_size, void* d_ws, size_t ws_size,
                              hipStream_t stream) {
    (void)in_sizes; (void)n_in; (void)out_size;
    const float* hidden = (const float*)d_in[0];
    const int* pos = (const int*)d_in[1];
    const float* wq = (const float*)d_in[2];
    const float* wk = (const float*)d_in[3];
    const float* wv = (const float*)d_in[4];
    const float* wo = (const float*)d_in[5];
    float* out = (float*)d_out;

    const int M = 4096;  // B*S
    char* ws = (char*)d_ws;
    size_t off = 0;
    auto alloc = [&](size_t bytes) { char* p = ws + off; off += bytes; return p; };
    __hip_bfloat16* Xb    = (__hip_bfloat16*)alloc((size_t)M * 4096 * 2);
    __hip_bfloat16* Wqkvt = (__hip_bfloat16*)alloc((size_t)6144 * 4096 * 2);
    __hip_bfloat16* Wot   = (__hip_bfloat16*)alloc((size_t)4096 * 4096 * 2);
    __hip_bfloat16* Qb    = (__hip_bfloat16*)alloc((size_t)M * 4096 * 2);
    __hip_bfloat16* Kb    = (__hip_bfloat16*)alloc((size_t)M * 1024 * 2);
    __hip_bfloat16* Vtt   = (__hip_bfloat16*)alloc((size_t)M * 1024 * 2);
    __hip_bfloat16* AO    = (__hip_bfloat16*)alloc((size_t)M * 4096 * 2);
    if (off > ws_size) return;

    cast_bf16_kernel<<<(M * 4096) / 1024, 256, 0, stream>>>(hidden, Xb);
    dim3 tb(32, 8);
    transpose_cast_kernel<<<dim3(128, 128), tb, 0, stream>>>(wq, Wqkvt, 4096, 4096);
    transpose_cast_kernel<<<dim3(32, 128),  tb, 0, stream>>>(wk, Wqkvt + (size_t)4096 * 4096, 4096, 1024);
    transpose_cast_kernel<<<dim3(32, 128),  tb, 0, stream>>>(wv, Wqkvt + (size_t)5120 * 4096, 4096, 1024);
    transpose_cast_kernel<<<dim3(128, 128), tb, 0, stream>>>(wo, Wot, 4096, 4096);

    gemm_qkv_kernel<<<dim3(48, 32), 256, 0, stream>>>(Xb, Wqkvt, Qb, Kb, Vtt);

    rope_kernel<<<(2 * 32 * 2048 * 64) / 256, 256, 0, stream>>>(Qb, pos, 32);
    rope_kernel<<<(2 * 8 * 2048 * 64) / 256, 256, 0, stream>>>(Kb, pos, 8);

    attn_kernel<<<dim3(32, 32, 2), 256, 0, stream>>>(Qb, Kb, Vtt, AO);

    gemm_out_kernel<<<dim3(16, 16), 512, 0, stream>>>(AO, Wot, out);
}